// Round 7
// baseline (279.733 us; speedup 1.0000x reference)
//
#include <hip/hip_runtime.h>
#include <hip/hip_bf16.h>
#include <cstddef>

using bf16 = __hip_bfloat16;
typedef __attribute__((ext_vector_type(4)))  short bf16x4;
typedef __attribute__((ext_vector_type(8)))  short bf16x8;
typedef __attribute__((ext_vector_type(4)))  float f32x4;
typedef __attribute__((ext_vector_type(16))) float f32x16;

#define B_   64
#define T_   512
#define V_   25
#define HD_  64
#define E_   48
#define NC_  60

__device__ __forceinline__ float b2f(bf16 x){ return __bfloat162float(x); }
__device__ __forceinline__ bf16  f2b(float x){ return __float2bfloat16(x); }
__device__ __forceinline__ unsigned short f2bits(float x){ return __builtin_bit_cast(unsigned short, f2b(x)); }
__device__ __forceinline__ float bits2f(unsigned short s){ return __builtin_bit_cast(float, ((unsigned)s)<<16); }
__device__ __forceinline__ float rbf(float x){ return bits2f(f2bits(x)); }   // round to bf16

// ---------------- prep: CSR of edges grouped by dst ----------------
__global__ void k_csr(const int* __restrict__ ei, int* __restrict__ offs, int* __restrict__ lst)
{
  if(threadIdx.x == 0){
    int cnt[V_], pos[V_];
    for(int v=0;v<V_;v++) cnt[v]=0;
    for(int e=0;e<E_;e++) cnt[ei[2*e+1]]++;
    int off = 0;
    for(int v=0;v<V_;v++){ offs[v]=off; pos[v]=off; off+=cnt[v]; }
    offs[V_] = off;
    for(int e=0;e<E_;e++){ int d = ei[2*e+1]; lst[pos[d]++] = ei[2*e+0]; }
  }
}

// ---------------- prep: weight packing ----------------
__global__ void k_wt(const float* __restrict__ c1W, const float* __restrict__ c2W,
                     const float* __restrict__ s2W, const float* __restrict__ W2,
                     bf16* __restrict__ Wb, bf16* __restrict__ Wb2, bf16* __restrict__ WbB)
{
  int i0 = blockIdx.x*blockDim.x + threadIdx.x, stride = gridDim.x*blockDim.x;
  for(int i = i0; i < 307200; i += stride){
    int hlo = i & 15, o = (i>>4)&63, kc = (i>>10)%12, v = i/12288;
    int ks = kc>>2, h = (kc&3)*16 + hlo;
    Wb[i] = f2b(c1W[(o*1600 + v*64 + h)*3 + ks]);
  }
  for(int i = i0; i < 24576; i += stride){
    int hlo = i & 15, o = (i>>4)&127, kc = i>>11;
    int ks = kc>>2, c = (kc&3)*16 + hlo;
    Wb2[i] = f2b(c2W[(o*64 + c)*3 + ks]);
  }
  for(int i = i0; i < 8192; i += stride){
    int j = i&7, l=(i>>3)&63, n=(i>>9)&3, kt=i>>11;
    int k = kt*32 + (l>>4)*8 + j;
    int h = n*16 + (l&15);
    float val = (k < 64) ? s2W[k*64 + h] : W2[(k-64)*64 + h];
    WbB[i] = f2b(val);
  }
}

// ---------------- GCN layer 1 stats-only (no H write; bias cancels in BN) ----------------
__global__ __launch_bounds__(512) void k_gcn1s(
    const float* __restrict__ X, const float* __restrict__ s1W, const float* __restrict__ W1,
    const int* __restrict__ offs, const int* __restrict__ lst, float* __restrict__ part)
{
  int b = blockIdx.y, t0 = blockIdx.x*16, tid = threadIdx.x;
  __shared__ float Xs[3][16][26], ag[3][16][26];
  __shared__ float sw[3][64], gw[3][64];
  __shared__ int so[V_+1], sl[E_];
  __shared__ float red[4][1024];
  if(tid < 192){ sw[tid/64][tid&63] = rbf(s1W[tid]); gw[tid/64][tid&63] = rbf(W1[tid]); }
  else if(tid >= 192 && tid < 192+V_+1) so[tid-192] = offs[tid-192];
  else if(tid >= 256 && tid < 256+E_) sl[tid-256] = lst[tid-256];
  for(int i=tid; i<1200; i+=512){
    int c = i/400, r = i%400, tl = r/25, v = r%25;
    Xs[c][tl][v] = rbf(X[((size_t)(b*3+c)*T_ + t0+tl)*V_ + v]);
  }
  __syncthreads();
  for(int i=tid; i<1200; i+=512){
    int c = i/400, r = i%400, tl = r/25, v = r%25;
    float s = 0.f;
    for(int e=so[v]; e<so[v+1]; e++) s += Xs[c][tl][sl[e]];
    ag[c][tl][v] = s;
  }
  __syncthreads();
  int t = tid>>5, l5 = tid&31, h8 = l5&7, vs = l5>>3;
  float swr[3][8], gwr[3][8];
  #pragma unroll
  for(int c=0;c<3;c++)
    #pragma unroll
    for(int j=0;j<8;j++){ swr[c][j]=sw[c][h8*8+j]; gwr[c][j]=gw[c][h8*8+j]; }
  float s8[8]={0,0,0,0,0,0,0,0}, q8[8]={0,0,0,0,0,0,0,0};
  for(int v=vs; v<V_; v+=4){
    float x0=Xs[0][t][v], x1=Xs[1][t][v], x2=Xs[2][t][v];
    float a0=ag[0][t][v], a1=ag[1][t][v], a2=ag[2][t][v];
    #pragma unroll
    for(int j=0;j<8;j++){
      float o = x0*swr[0][j] + x1*swr[1][j] + x2*swr[2][j]
              + a0*gwr[0][j] + a1*gwr[1][j] + a2*gwr[2][j];
      s8[j] += o; q8[j] += o*o;
    }
  }
  size_t pb = ((size_t)blockIdx.x*64 + blockIdx.y)*2048;
  #pragma unroll
  for(int j=0;j<8;j++) red[vs][t*64 + h8*8 + j] = s8[j];
  __syncthreads();
  for(int i=tid; i<1024; i+=512)
    part[pb + i] = red[0][i]+red[1][i]+red[2][i]+red[3][i];
  __syncthreads();
  #pragma unroll
  for(int j=0;j<8;j++) red[vs][t*64 + h8*8 + j] = q8[j];
  __syncthreads();
  for(int i=tid; i<1024; i+=512)
    part[pb + 1024 + i] = red[0][i]+red[1][i]+red[2][i]+red[3][i];
}

// ---------------- per-(t,h) BN finalize from block partials ----------------
__global__ void k_bnfin_th(const float* __restrict__ part,
                           const float* __restrict__ g, const float* __restrict__ bt,
                           float* __restrict__ scale, float* __restrict__ shift)
{
  int i = blockIdx.x*blockDim.x + threadIdx.x;
  if(i < T_*HD_){
    int h = i & 63, t = i >> 6, bx = t >> 4, tl = t & 15;
    const float* p = part + ((size_t)bx*64)*2048 + tl*64 + h;
    float s = 0.f, q = 0.f;
    for(int b=0;b<64;b++){ s += p[(size_t)b*2048]; q += p[(size_t)b*2048 + 1024]; }
    float m = s * (1.0f/1600.0f);
    float v = q * (1.0f/1600.0f) - m*m;
    float r = rsqrtf(fmaxf(v, 0.f) + 1e-5f);
    float sc = g[h]*r;
    scale[i] = sc;
    shift[i] = bt[h] - m*sc;
  }
}

// ---------------- GCN layer 2: recompute H1 from X, MFMA, write H2 ----------------
__global__ __launch_bounds__(512,4) void k_gcn2(
    const float* __restrict__ X,
    const float* __restrict__ s1W, const float* __restrict__ W1,
    const float* __restrict__ scale1, const float* __restrict__ shift1,
    const bf16* __restrict__ WbB,
    const int* __restrict__ offs, const int* __restrict__ lst,
    bf16* __restrict__ Hout, float* __restrict__ part)
{
  int tid = threadIdx.x, lane = tid & 63, wid = tid >> 6;
  int b = blockIdx.y, t0 = blockIdx.x*16;
  __shared__ short Zs[400*72];          // 57,600 B (reused as red f32[8][1024])
  __shared__ short WbBs[8192];          // 16,384 B
  __shared__ unsigned int pss[1024];    //  4,096 B packed {shift,scale} bf16
  __shared__ short Xs[1248];            //  2,496 B bf16 [3][16][26]
  __shared__ short swg[384];            //    768 B bf16: sw[3][64] then gw[3][64]
  __shared__ unsigned char soc[32], slc[48];

  if(tid < V_+1) soc[tid] = (unsigned char)offs[tid];
  else if(tid >= 64 && tid < 64+E_) slc[tid-64] = (unsigned char)lst[tid-64];
  else if(tid >= 128){
    int i = tid - 128;
    float w = (i < 192) ? s1W[i] : W1[i-192];
    swg[i] = (short)f2bits(w);
  }
  for(int i=tid; i<1024; i+=512){
    pss[i] = ((unsigned)f2bits(shift1[t0*64+i])<<16) | f2bits(scale1[t0*64+i]);
    *(bf16x8*)&WbBs[i*8] = *(const bf16x8*)&WbB[i*8];
  }
  for(int i=tid; i<1248; i+=512){
    int c = i/416, r = i - c*416, tl = r/26, v = r - tl*26;
    short val = 0;
    if(v < 25) val = (short)f2bits(X[((size_t)(b*3+c)*T_ + t0+tl)*V_ + v]);
    Xs[i] = val;
  }
  __syncthreads();

  // ---- recompute H1, apply bn1+relu, stage into Zs rows (v*16+tl), stride 72 ----
  for(int c=tid; c<3200; c+=512){
    int h8 = c & 7, rr = c >> 3, tl = rr/25, v = rr - tl*25;
    int xb = tl*26;
    float x0 = bits2f((unsigned short)Xs[xb+v]);
    float x1 = bits2f((unsigned short)Xs[416+xb+v]);
    float x2 = bits2f((unsigned short)Xs[832+xb+v]);
    float a0=0.f, a1=0.f, a2=0.f;
    int e1 = soc[v+1];
    for(int e=soc[v]; e<e1; e++){
      int u = slc[e];
      a0 += bits2f((unsigned short)Xs[xb+u]);
      a1 += bits2f((unsigned short)Xs[416+xb+u]);
      a2 += bits2f((unsigned short)Xs[832+xb+u]);
    }
    bf16x8 sv0 = *(const bf16x8*)&swg[h8*8];
    bf16x8 sv1 = *(const bf16x8*)&swg[64+h8*8];
    bf16x8 sv2 = *(const bf16x8*)&swg[128+h8*8];
    bf16x8 gv0 = *(const bf16x8*)&swg[192+h8*8];
    bf16x8 gv1 = *(const bf16x8*)&swg[256+h8*8];
    bf16x8 gv2 = *(const bf16x8*)&swg[320+h8*8];
    uint4 u0 = *(const uint4*)&pss[tl*64 + h8*8];
    uint4 u1 = *(const uint4*)&pss[tl*64 + h8*8 + 4];
    unsigned int uu[8] = {u0.x,u0.y,u0.z,u0.w,u1.x,u1.y,u1.z,u1.w};
    bf16x8 o;
    #pragma unroll
    for(int j=0;j<8;j++){
      float val = x0*bits2f((unsigned short)sv0[j]) + x1*bits2f((unsigned short)sv1[j]) + x2*bits2f((unsigned short)sv2[j])
                + a0*bits2f((unsigned short)gv0[j]) + a1*bits2f((unsigned short)gv1[j]) + a2*bits2f((unsigned short)gv2[j]);
      float y = val*bits2f((unsigned short)(uu[j]&0xffffu)) + bits2f((unsigned short)(uu[j]>>16));
      o[j] = (short)f2bits(fmaxf(y, 0.f));
    }
    *(bf16x8*)&Zs[(v*16 + tl)*72 + h8*8] = o;
  }
  __syncthreads();

  // ---- MFMA with in-register neighbor aggregation ----
  int l15 = lane & 15, cg = (lane>>4)*8;
  f32x4 accs[4][4] = {};
  #pragma unroll
  for(int vi=0; vi<4; vi++){
    int v = wid + vi*8;
    if(v < V_){
      const short* rowp = &Zs[(v*16 + l15)*72 + cg];
      bf16x8 a0 = *(const bf16x8*)rowp;
      bf16x8 a1 = *(const bf16x8*)(rowp + 32);
      float s0[8]={0,0,0,0,0,0,0,0}, s1[8]={0,0,0,0,0,0,0,0};
      int e1 = soc[v+1];
      for(int e=soc[v]; e<e1; e++){
        int u = slc[e];
        const short* np = &Zs[(u*16 + l15)*72 + cg];
        bf16x8 n0 = *(const bf16x8*)np;
        bf16x8 n1 = *(const bf16x8*)(np + 32);
        #pragma unroll
        for(int j=0;j<8;j++){ s0[j] += bits2f((unsigned short)n0[j]); s1[j] += bits2f((unsigned short)n1[j]); }
      }
      bf16x8 a2, a3;
      #pragma unroll
      for(int j=0;j<8;j++){ a2[j] = (short)f2bits(s0[j]); a3[j] = (short)f2bits(s1[j]); }
      #pragma unroll
      for(int n=0;n<4;n++){
        bf16x8 b0 = *(const bf16x8*)&WbBs[(( 0+n)*64 + lane)*8];
        accs[vi][n] = __builtin_amdgcn_mfma_f32_16x16x32_bf16(a0, b0, accs[vi][n], 0, 0, 0);
        bf16x8 b1 = *(const bf16x8*)&WbBs[(( 4+n)*64 + lane)*8];
        accs[vi][n] = __builtin_amdgcn_mfma_f32_16x16x32_bf16(a1, b1, accs[vi][n], 0, 0, 0);
        bf16x8 b2 = *(const bf16x8*)&WbBs[(( 8+n)*64 + lane)*8];
        accs[vi][n] = __builtin_amdgcn_mfma_f32_16x16x32_bf16(a2, b2, accs[vi][n], 0, 0, 0);
        bf16x8 b3 = *(const bf16x8*)&WbBs[((12+n)*64 + lane)*8];
        accs[vi][n] = __builtin_amdgcn_mfma_f32_16x16x32_bf16(a3, b3, accs[vi][n], 0, 0, 0);
      }
    }
  }
  __syncthreads();

  // ---- epilogue: stats + bf16 transpose via Zs (no bias: s2b cancels in BN2) ----
  int tlb = (lane>>4)*4;
  f32x4 ssum[4] = {}, ssq[4] = {};
  #pragma unroll
  for(int vi=0; vi<4; vi++){
    int v = wid + vi*8;
    if(v < V_){
      #pragma unroll
      for(int n=0;n<4;n++){
        #pragma unroll
        for(int j=0;j<4;j++){
          float val = accs[vi][n][j];
          ssum[n][j] += val; ssq[n][j] += val*val;
          Zs[((tlb+j)*25 + v)*72 + n*16 + l15] = (short)f2bits(val);
        }
      }
    }
  }
  __syncthreads();

  bf16* hbout = Hout + ((size_t)b*T_ + t0)*V_*64;
  for(int c=tid; c<3200; c+=512){
    bf16x8 o = *(const bf16x8*)&Zs[(c>>3)*72 + (c&7)*8];
    *(bf16x8*)&hbout[(size_t)c*8] = o;
  }
  __syncthreads();

  float* red = (float*)Zs;
  size_t pb = ((size_t)blockIdx.x*64 + blockIdx.y)*2048;
  #pragma unroll
  for(int n=0;n<4;n++)
    #pragma unroll
    for(int j=0;j<4;j++)
      red[wid*1024 + (tlb+j)*64 + n*16 + l15] = ssum[n][j];
  __syncthreads();
  for(int i=tid; i<1024; i+=512){
    float s = 0.f;
    #pragma unroll
    for(int w=0;w<8;w++) s += red[w*1024 + i];
    part[pb + i] = s;
  }
  __syncthreads();
  #pragma unroll
  for(int n=0;n<4;n++)
    #pragma unroll
    for(int j=0;j<4;j++)
      red[wid*1024 + (tlb+j)*64 + n*16 + l15] = ssq[n][j];
  __syncthreads();
  for(int i=tid; i<1024; i+=512){
    float q = 0.f;
    #pragma unroll
    for(int w=0;w<8;w++) q += red[w*1024 + i];
    part[pb + 1024 + i] = q;
  }
}

// ---------------- conv1 via MFMA, K-split over 2 v-groups ----------------
__device__ __forceinline__ bf16x8 loadH8(const bf16* H, int b, int v, int t0, int s){
  int ti = s>>3, h0 = (s&7)*8, t = t0-1+ti;
  bf16x8 r = {0,0,0,0,0,0,0,0};
  if(t >= 0 && t < T_) r = *(const bf16x8*)&H[(((size_t)b*T_+t)*V_ + v)*HD_ + h0];
  return r;
}

__device__ __forceinline__ void xform_store(short* zbuf, const unsigned int* sshf, int s, bf16x8 raw){
  int ti = s>>3, h0 = (s&7)*8;
  uint4 u0 = *(const uint4*)&sshf[ti*64 + h0];
  uint4 u1 = *(const uint4*)&sshf[ti*64 + h0 + 4];
  unsigned int uu[8] = {u0.x,u0.y,u0.z,u0.w,u1.x,u1.y,u1.z,u1.w};
  bf16x8 outv;
  #pragma unroll
  for(int j=0;j<8;j++){
    float scl = bits2f((unsigned short)(uu[j] & 0xffffu));
    float shf = bits2f((unsigned short)(uu[j] >> 16));
    float x = bits2f((unsigned short)raw[j]);
    outv[j] = (short)f2bits(fmaxf(x*scl + shf, 0.f));
  }
  *(bf16x8*)&zbuf[ti*72 + h0] = outv;
}

__global__ __launch_bounds__(256,4) void k_conv1(
    const bf16* __restrict__ H, const float* __restrict__ scale2, const float* __restrict__ shift2,
    const bf16* __restrict__ Wb, float* __restrict__ P)
{
  int b = blockIdx.y, t0 = blockIdx.x*64, vg = blockIdx.z, tid = threadIdx.x;
  int lane = tid & 63, w = tid >> 6;
  int v0 = vg ? 13 : 0, nv = vg ? 12 : 13;
  __shared__ unsigned int sshf[66*64];
  __shared__ short zs[2][66*72];

  for(int i = tid; i < 66*64; i += 256){
    int ti = i>>6, h = i&63, t = t0-1+ti;
    unsigned int u = 0;
    if(t >= 0 && t < T_){
      u = ((unsigned)f2bits(shift2[t*64+h])<<16) | f2bits(scale2[t*64+h]);
    }
    sshf[i] = u;
  }
  __syncthreads();

  {
    bf16x8 a0 = loadH8(H,b,v0,t0,tid);
    bf16x8 a1 = loadH8(H,b,v0,t0,tid+256);
    bf16x8 a2 = {0,0,0,0,0,0,0,0};
    if(tid<16) a2 = loadH8(H,b,v0,t0,tid+512);
    xform_store(zs[0], sshf, tid, a0);
    xform_store(zs[0], sshf, tid+256, a1);
    if(tid<16) xform_store(zs[0], sshf, tid+512, a2);
  }
  __syncthreads();

  int ow = w & 1, twv = (w>>1)*32;
  int o0 = ow*32;
  f32x16 acc = {};
  for(int i=0; i<nv; i++){
    int v = v0 + i, cur = i & 1;
    bf16x8 a0={0,0,0,0,0,0,0,0}, a1={0,0,0,0,0,0,0,0}, a2={0,0,0,0,0,0,0,0};
    if(i+1 < nv){
      a0 = loadH8(H,b,v+1,t0,tid);
      a1 = loadH8(H,b,v+1,t0,tid+256);
      if(tid<16) a2 = loadH8(H,b,v+1,t0,tid+512);
    }
    const short* zbuf = zs[cur];
    #pragma unroll
    for(int kc=0; kc<12; kc++){
      int ks = kc>>2;
      bf16x8 af = *(const bf16x8*)&Wb[((v*12+kc)*64 + o0 + (lane&31))*16 + (lane>>5)*8];
      int row = twv + (lane&31) + ks;
      int col = (kc&3)*16 + (lane>>5)*8;
      bf16x8 bfr = *(const bf16x8*)&zbuf[row*72 + col];
      acc = __builtin_amdgcn_mfma_f32_32x32x16_bf16(af, bfr, acc, 0, 0, 0);
    }
    if(i+1 < nv){
      short* znext = zs[cur^1];
      xform_store(znext, sshf, tid, a0);
      xform_store(znext, sshf, tid+256, a1);
      if(tid<16) xform_store(znext, sshf, tid+512, a2);
    }
    __syncthreads();
  }
  int t = t0 + twv + (lane&31);
  size_t pbase = ((size_t)vg*B_ + b)*64;
  #pragma unroll
  for(int r=0;r<16;r++){
    int o = o0 + (r&3) + 8*(r>>2) + 4*(lane>>5);
    P[(pbase + o)*T_ + t] = acc[r];
  }
}

// ---------------- reduce partial planes -> C1 bf16 (no bias) + BN3 stats ----------------
__global__ __launch_bounds__(128) void k_red1(
    const float* __restrict__ P, bf16* __restrict__ C1b,
    float* __restrict__ sum3, float* __restrict__ sq3)
{
  int o = blockIdx.x, b = blockIdx.y, tid = threadIdx.x;
  size_t base = ((size_t)b*64 + o)*T_ + tid*4;
  float4 x = *(const float4*)&P[base];
  float4 y = *(const float4*)&P[2097152 + base];
  float4 r;
  r.x = x.x + y.x; r.y = x.y + y.y; r.z = x.z + y.z; r.w = x.w + y.w;
  bf16x4 st;
  st[0]=(short)f2bits(r.x); st[1]=(short)f2bits(r.y); st[2]=(short)f2bits(r.z); st[3]=(short)f2bits(r.w);
  *(bf16x4*)&C1b[base] = st;
  float s = r.x + r.y + r.z + r.w;
  float q = r.x*r.x + r.y*r.y + r.z*r.z + r.w*r.w;
  for(int off=32; off; off>>=1){ s += __shfl_down(s, off); q += __shfl_down(q, off); }
  __shared__ float rs[2], rq[2];
  if((tid&63)==0){ rs[tid>>6]=s; rq[tid>>6]=q; }
  __syncthreads();
  if(tid==0){ atomicAdd(&sum3[o], rs[0]+rs[1]); atomicAdd(&sq3[o], rq[0]+rq[1]); }
}

// ---------------- per-channel BN finalize ----------------
__global__ void k_bnfin_ch(const float* __restrict__ sum, const float* __restrict__ sq,
                           const float* __restrict__ g, const float* __restrict__ bt,
                           float* __restrict__ scale, float* __restrict__ shift,
                           int nch, float inv_count)
{
  int i = blockIdx.x*blockDim.x + threadIdx.x;
  if(i < nch){
    float m = sum[i]*inv_count;
    float v = sq[i]*inv_count - m*m;
    float r = rsqrtf(fmaxf(v, 0.f) + 1e-5f);
    float sc = g[i]*r;
    scale[i]=sc; shift[i]=bt[i]-m*sc;
  }
}

// ---------------- conv2 via MFMA (C1 bf16 in; no bias: c2b cancels in BN4) ----------------
__global__ __launch_bounds__(256) void k_conv2(
    const bf16* __restrict__ C1b, const float* __restrict__ scale3, const float* __restrict__ shift3,
    const bf16* __restrict__ Wb2, float* __restrict__ C2)
{
  int b = blockIdx.y, t0 = blockIdx.x*64, tid = threadIdx.x;
  int lane = tid & 63, w = tid >> 6;
  __shared__ short zT[68*72];
  __shared__ float scl[64], shf[64];
  if(tid < 64){ scl[tid]=scale3[tid]; shf[tid]=shift3[tid]; }
  __syncthreads();
  for(int i=tid; i<4352; i+=256){
    int c = i/68, r = i%68, t = t0 - 2 + r;
    float val = 0.f;
    if(t >= 0 && t < T_) val = fmaxf(bits2f((unsigned short)__builtin_bit_cast(short, C1b[((size_t)b*64+c)*T_ + t]))*scl[c] + shf[c], 0.f);
    zT[r*72 + c] = (short)f2bits(val);
  }
  __syncthreads();
  int o0 = w*32;
  #pragma unroll
  for(int tt=0; tt<2; tt++){
    int twv = tt*32;
    f32x16 acc = {};
    #pragma unroll
    for(int kc=0; kc<12; kc++){
      bf16x8 af = *(const bf16x8*)&Wb2[((kc*128) + o0 + (lane&31))*16 + (lane>>5)*8];
      bf16x8 bfr = *(const bf16x8*)&zT[(twv + (lane&31) + 2*(kc>>2))*72 + (kc&3)*16 + (lane>>5)*8];
      acc = __builtin_amdgcn_mfma_f32_32x32x16_bf16(af, bfr, acc, 0, 0, 0);
    }
    int t = t0 + twv + (lane&31);
    #pragma unroll
    for(int r=0;r<16;r++){
      int o = o0 + (r&3) + 8*(r>>2) + 4*(lane>>5);
      C2[((size_t)b*128 + o)*T_ + t] = acc[r];
    }
  }
}

// ---------------- per-channel stats over C2 ----------------
__global__ __launch_bounds__(256) void k_stats_ch(const float* __restrict__ C,
    float* __restrict__ sum, float* __restrict__ sq, int nch)
{
  int o = blockIdx.x, tid = threadIdx.x;
  float s=0.f, q=0.f;
  for(int idx = tid; idx < 64*128; idx += 256){
    int b = idx >> 7, t4 = idx & 127;
    float4 vv = *(const float4*)&C[((size_t)(b*nch+o))*T_ + t4*4];
    s += vv.x+vv.y+vv.z+vv.w;
    q += vv.x*vv.x + vv.y*vv.y + vv.z*vv.z + vv.w*vv.w;
  }
  for(int off=32; off; off>>=1){ s += __shfl_down(s, off); q += __shfl_down(q, off); }
  __shared__ float rs[4], rq[4];
  if((tid&63)==0){ rs[tid>>6]=s; rq[tid>>6]=q; }
  __syncthreads();
  if(tid==0){ sum[o] = rs[0]+rs[1]+rs[2]+rs[3]; sq[o] = rq[0]+rq[1]+rq[2]+rq[3]; }
}

// ---------------- head ----------------
__global__ __launch_bounds__(256) void k_head(
    const float* __restrict__ C2, const float* __restrict__ scale4, const float* __restrict__ shift4,
    const float* __restrict__ fcW, const float* __restrict__ fcb, float* __restrict__ out)
{
  int b = blockIdx.x, tid = threadIdx.x;
  __shared__ float mean[128];
  __shared__ float ms[256];
  int ch = tid >> 1, p = tid & 1;
  float scl = scale4[ch], shf = shift4[ch];
  const float* src = C2 + ((size_t)b*128 + ch)*T_ + p*256;
  float s = 0.f;
  for(int i=0;i<64;i++){
    float4 v4 = *(const float4*)&src[i*4];
    s += fmaxf(v4.x*scl + shf, 0.f) + fmaxf(v4.y*scl + shf, 0.f)
       + fmaxf(v4.z*scl + shf, 0.f) + fmaxf(v4.w*scl + shf, 0.f);
  }
  ms[tid] = s;
  __syncthreads();
  if(tid < 128) mean[tid] = (ms[2*tid] + ms[2*tid+1]) * (1.0f/512.0f);
  __syncthreads();
  if(tid < NC_){
    float acc = fcb[tid];
    for(int c=0;c<128;c++) acc += mean[c]*fcW[c*NC_ + tid];
    out[b*NC_ + tid] = acc;
  }
}

// ---------------- launch ----------------
extern "C" void kernel_launch(void* const* d_in, const int* in_sizes, int n_in,
                              void* d_out, int out_size, void* d_ws, size_t ws_size,
                              hipStream_t stream)
{
  const float* X   = (const float*)d_in[0];
  const int*   ei  = (const int*)  d_in[1];
  const float* W1  = (const float*)d_in[2];
  const float* s1W = (const float*)d_in[3];
  const float* g1  = (const float*)d_in[5];
  const float* b1  = (const float*)d_in[6];
  const float* W2  = (const float*)d_in[7];
  const float* s2W = (const float*)d_in[8];
  const float* g2  = (const float*)d_in[10];
  const float* b2  = (const float*)d_in[11];
  const float* c1W = (const float*)d_in[12];
  const float* tg1 = (const float*)d_in[14];
  const float* tb1 = (const float*)d_in[15];
  const float* c2W = (const float*)d_in[16];
  const float* tg2 = (const float*)d_in[18];
  const float* tb2 = (const float*)d_in[19];
  const float* fcW = (const float*)d_in[20];
  const float* fcb = (const float*)d_in[21];

  char* ws = (char*)d_ws;
  bf16*  H     = (bf16*) (ws);                       // H2 only, 104,857,600 B
  bf16*  C1b   = (bf16*) (ws + 104857600);           // 4 MB bf16
  // 16.7 MB region multi-used (dependency-ordered): BN partials -> conv1 P -> conv2 C2
  float* part  = (float*)(ws + 113246208);
  float* P     = part;
  float* C2    = part;
  bf16*  Wb    = (bf16*) (ws + 130023424);
  bf16*  Wb2   = (bf16*) (ws + 131252224);
  bf16*  WbB   = (bf16*) (ws + 131350528);
  float* stats = (float*)(ws + 131366912);
  float* sum3 = stats + 131072;   float* sq3 = sum3 + 64;
  float* sum4 = sq3 + 64;         float* sq4 = sum4 + 128;
  float* scale1 = stats + 131456; float* shift1 = scale1 + 32768;
  float* scale2 = shift1 + 32768; float* shift2 = scale2 + 32768;
  float* scale3 = shift2 + 32768; float* shift3 = scale3 + 64;
  float* scale4 = shift3 + 64;    float* shift4 = scale4 + 128;
  int* csr_off = (int*)(shift4 + 128);
  int* csr_lst = csr_off + 32;

  hipMemsetAsync(sum3, 0, 384*sizeof(float), stream);
  k_csr<<<1, 64, 0, stream>>>(ei, csr_off, csr_lst);
  k_wt<<<256, 256, 0, stream>>>(c1W, c2W, s2W, W2, Wb, Wb2, WbB);

  k_gcn1s<<<dim3(T_/16, B_), 512, 0, stream>>>(X, s1W, W1, csr_off, csr_lst, part);
  k_bnfin_th<<<128, 256, 0, stream>>>(part, g1, b1, scale1, shift1);
  k_gcn2<<<dim3(T_/16, B_), 512, 0, stream>>>(X, s1W, W1, scale1, shift1, WbB, csr_off, csr_lst, H, part);
  k_bnfin_th<<<128, 256, 0, stream>>>(part, g2, b2, scale2, shift2);
  k_conv1<<<dim3(8, B_, 2), 256, 0, stream>>>(H, scale2, shift2, Wb, P);
  k_red1<<<dim3(64, B_), 128, 0, stream>>>(P, C1b, sum3, sq3);
  k_bnfin_ch<<<1, 64, 0, stream>>>(sum3, sq3, tg1, tb1, scale3, shift3, 64, 1.0f/32768.0f);
  k_conv2<<<dim3(8, B_), 256, 0, stream>>>(C1b, scale3, shift3, Wb2, C2);
  k_stats_ch<<<128, 256, 0, stream>>>(C2, sum4, sq4, 128);
  k_bnfin_ch<<<1, 128, 0, stream>>>(sum4, sq4, tg2, tb2, scale4, shift4, 128, 1.0f/32768.0f);
  k_head<<<B_, 256, 0, stream>>>(C2, scale4, shift4, fcW, fcb, (float*)d_out);
}

// Round 8
// 262.880 us; speedup vs baseline: 1.0641x; 1.0641x over previous
//
#include <hip/hip_runtime.h>
#include <hip/hip_bf16.h>
#include <cstddef>

using bf16 = __hip_bfloat16;
typedef __attribute__((ext_vector_type(4)))  short bf16x4;
typedef __attribute__((ext_vector_type(8)))  short bf16x8;
typedef __attribute__((ext_vector_type(4)))  float f32x4;
typedef __attribute__((ext_vector_type(16))) float f32x16;

#define B_   64
#define T_   512
#define V_   25
#define HD_  64
#define E_   48
#define NC_  60

__device__ __forceinline__ bf16  f2b(float x){ return __float2bfloat16(x); }
__device__ __forceinline__ unsigned short f2bits(float x){ return __builtin_bit_cast(unsigned short, f2b(x)); }
__device__ __forceinline__ float bits2f(unsigned short s){ return __builtin_bit_cast(float, ((unsigned)s)<<16); }

// ---------------- prep: CSR of edges grouped by dst ----------------
__global__ void k_csr(const int* __restrict__ ei, int* __restrict__ offs, int* __restrict__ lst)
{
  if(threadIdx.x == 0){
    int cnt[V_], pos[V_];
    for(int v=0;v<V_;v++) cnt[v]=0;
    for(int e=0;e<E_;e++) cnt[ei[2*e+1]]++;
    int off = 0;
    for(int v=0;v<V_;v++){ offs[v]=off; pos[v]=off; off+=cnt[v]; }
    offs[V_] = off;
    for(int e=0;e<E_;e++){ int d = ei[2*e+1]; lst[pos[d]++] = ei[2*e+0]; }
  }
}

// ---------------- prep: weight packing ----------------
__global__ void k_wt(const float* __restrict__ c1W, const float* __restrict__ c2W,
                     const float* __restrict__ s2W, const float* __restrict__ W2,
                     const float* __restrict__ s1W, const float* __restrict__ W1,
                     bf16* __restrict__ Wb, bf16* __restrict__ Wb2,
                     bf16* __restrict__ WbB, bf16* __restrict__ W6f)
{
  int i0 = blockIdx.x*blockDim.x + threadIdx.x, stride = gridDim.x*blockDim.x;
  for(int i = i0; i < 307200; i += stride){
    int hlo = i & 15, o = (i>>4)&63, kc = (i>>10)%12, v = i/12288;
    int ks = kc>>2, h = (kc&3)*16 + hlo;
    Wb[i] = f2b(c1W[(o*1600 + v*64 + h)*3 + ks]);
  }
  for(int i = i0; i < 24576; i += stride){
    int hlo = i & 15, o = (i>>4)&127, kc = i>>11;
    int ks = kc>>2, c = (kc&3)*16 + hlo;
    Wb2[i] = f2b(c2W[(o*64 + c)*3 + ks]);
  }
  for(int i = i0; i < 8192; i += stride){
    int j = i&7, l=(i>>3)&63, n=(i>>9)&3, kt=i>>11;
    int k = kt*32 + (l>>4)*8 + j;
    int h = n*16 + (l&15);
    float val = (k < 64) ? s2W[k*64 + h] : W2[(k-64)*64 + h];
    WbB[i] = f2b(val);
  }
  // W6 B-frags for the layer-1 recompute: W6[k][h], k=0..2 -> s1W, 3..5 -> W1, else 0
  for(int i = i0; i < 2048; i += stride){
    int j = i&7, l=(i>>3)&63, n=(i>>9)&3;
    int k = (l>>4)*8 + j, h = n*16 + (l&15);
    float val = 0.f;
    if(k < 3) val = s1W[k*64 + h];
    else if(k < 6) val = W1[(k-3)*64 + h];
    W6f[i] = f2b(val);
  }
}

// ---------------- GCN layer 1 stats-only via MFMA recompute ----------------
__global__ __launch_bounds__(512) void k_gcn1s(
    const float* __restrict__ X, const bf16* __restrict__ W6f,
    const int* __restrict__ offs, const int* __restrict__ lst, float* __restrict__ part)
{
  int tid = threadIdx.x, lane = tid & 63, wid = tid >> 6;
  int b = blockIdx.y, t0 = blockIdx.x*16;
  __shared__ short Z6[3200];
  __shared__ short Xs[1248];
  __shared__ float red[8192];
  __shared__ unsigned char soc[32], slc[48];

  bf16x8 w6[4];
  #pragma unroll
  for(int n=0;n<4;n++) w6[n] = *(const bf16x8*)&W6f[(n*64 + lane)*8];

  if(tid < V_+1) soc[tid] = (unsigned char)offs[tid];
  else if(tid >= 64 && tid < 64+E_) slc[tid-64] = (unsigned char)lst[tid-64];
  for(int i=tid; i<1248; i+=512){
    int c = i/416, r = i - c*416, tl = r/26, v = r - tl*26;
    short val = 0;
    if(v < 25) val = (short)f2bits(X[((size_t)(b*3+c)*T_ + t0+tl)*V_ + v]);
    Xs[i] = val;
  }
  __syncthreads();
  if(tid < 400){
    int v = tid>>4, tl = tid&15, xb = tl*26;
    float a0=0.f, a1=0.f, a2=0.f;
    int e1 = soc[v+1];
    for(int e=soc[v]; e<e1; e++){
      int u = slc[e];
      a0 += bits2f((unsigned short)Xs[xb+u]);
      a1 += bits2f((unsigned short)Xs[416+xb+u]);
      a2 += bits2f((unsigned short)Xs[832+xb+u]);
    }
    bf16x8 z;
    z[0]=Xs[xb+v]; z[1]=Xs[416+xb+v]; z[2]=Xs[832+xb+v];
    z[3]=(short)f2bits(a0); z[4]=(short)f2bits(a1); z[5]=(short)f2bits(a2);
    z[6]=0; z[7]=0;
    *(bf16x8*)&Z6[tid*8] = z;
  }
  __syncthreads();

  int l15 = lane & 15, tlb = (lane>>4)*4;
  f32x4 ssum[4] = {}, ssq[4] = {};
  #pragma unroll
  for(int vi=0; vi<4; vi++){
    int v = wid + vi*8;
    if(v < V_){
      bf16x8 af = {0,0,0,0,0,0,0,0};
      if(lane < 16) af = *(const bf16x8*)&Z6[(v*16 + lane)*8];
      #pragma unroll
      for(int n=0;n<4;n++){
        f32x4 c = {};
        c = __builtin_amdgcn_mfma_f32_16x16x32_bf16(af, w6[n], c, 0, 0, 0);
        #pragma unroll
        for(int j=0;j<4;j++){ float val = c[j]; ssum[n][j] += val; ssq[n][j] += val*val; }
      }
    }
  }
  #pragma unroll
  for(int n=0;n<4;n++)
    #pragma unroll
    for(int j=0;j<4;j++)
      red[wid*1024 + (tlb+j)*64 + n*16 + l15] = ssum[n][j];
  __syncthreads();
  size_t pb = ((size_t)blockIdx.x*64 + blockIdx.y)*2048;
  for(int i=tid; i<1024; i+=512){
    float s = 0.f;
    #pragma unroll
    for(int w=0;w<8;w++) s += red[w*1024 + i];
    part[pb + i] = s;
  }
  __syncthreads();
  #pragma unroll
  for(int n=0;n<4;n++)
    #pragma unroll
    for(int j=0;j<4;j++)
      red[wid*1024 + (tlb+j)*64 + n*16 + l15] = ssq[n][j];
  __syncthreads();
  for(int i=tid; i<1024; i+=512){
    float q = 0.f;
    #pragma unroll
    for(int w=0;w<8;w++) q += red[w*1024 + i];
    part[pb + 1024 + i] = q;
  }
}

// ---------------- per-(t,h) BN finalize from block partials ----------------
__global__ void k_bnfin_th(const float* __restrict__ part,
                           const float* __restrict__ g, const float* __restrict__ bt,
                           float* __restrict__ scale, float* __restrict__ shift)
{
  int i = blockIdx.x*blockDim.x + threadIdx.x;
  if(i < T_*HD_){
    int h = i & 63, t = i >> 6, bx = t >> 4, tl = t & 15;
    const float* p = part + ((size_t)bx*64)*2048 + tl*64 + h;
    float s = 0.f, q = 0.f;
    for(int b=0;b<64;b++){ s += p[(size_t)b*2048]; q += p[(size_t)b*2048 + 1024]; }
    float m = s * (1.0f/1600.0f);
    float v = q * (1.0f/1600.0f) - m*m;
    float r = rsqrtf(fmaxf(v, 0.f) + 1e-5f);
    float sc = g[h]*r;
    scale[i] = sc;
    shift[i] = bt[h] - m*sc;
  }
}

// ---------------- GCN layer 2: MFMA recompute of H1 + MFMA layer-2, write H2 ----------------
__global__ __launch_bounds__(512,4) void k_gcn2(
    const float* __restrict__ X,
    const float* __restrict__ scale1, const float* __restrict__ shift1,
    const bf16* __restrict__ W6f, const bf16* __restrict__ WbB,
    const int* __restrict__ offs, const int* __restrict__ lst,
    bf16* __restrict__ Hout, float* __restrict__ part)
{
  int tid = threadIdx.x, lane = tid & 63, wid = tid >> 6;
  int b = blockIdx.y, t0 = blockIdx.x*16;
  __shared__ short Zs[400*72];          // 57.6 KB; also hosts Z6/Xs (phase A) and red (stats)
  __shared__ short WbBs[8192];          // 16 KB
  __shared__ unsigned int pss[1024];    // 4 KB packed {shift,scale}
  __shared__ unsigned char soc[32], slc[48];
  short* Z6 = Zs;          // 3200 shorts, dead after pass-1 MFMA reads
  short* Xs = Zs + 3200;   // 1248 shorts, dead after Z6 build

  bf16x8 w6[4];
  #pragma unroll
  for(int n=0;n<4;n++) w6[n] = *(const bf16x8*)&W6f[(n*64 + lane)*8];

  if(tid < V_+1) soc[tid] = (unsigned char)offs[tid];
  else if(tid >= 64 && tid < 64+E_) slc[tid-64] = (unsigned char)lst[tid-64];
  for(int i=tid; i<1024; i+=512){
    pss[i] = ((unsigned)f2bits(shift1[t0*64+i])<<16) | f2bits(scale1[t0*64+i]);
    *(bf16x8*)&WbBs[i*8] = *(const bf16x8*)&WbB[i*8];
  }
  for(int i=tid; i<1248; i+=512){
    int c = i/416, r = i - c*416, tl = r/26, v = r - tl*26;
    short val = 0;
    if(v < 25) val = (short)f2bits(X[((size_t)(b*3+c)*T_ + t0+tl)*V_ + v]);
    Xs[i] = val;
  }
  __syncthreads();

  // build Z6 rows (r = v*16+tl): {x0,x1,x2,a0,a1,a2,0,0}
  if(tid < 400){
    int v = tid>>4, tl = tid&15, xb = tl*26;
    float a0=0.f, a1=0.f, a2=0.f;
    int e1 = soc[v+1];
    for(int e=soc[v]; e<e1; e++){
      int u = slc[e];
      a0 += bits2f((unsigned short)Xs[xb+u]);
      a1 += bits2f((unsigned short)Xs[416+xb+u]);
      a2 += bits2f((unsigned short)Xs[832+xb+u]);
    }
    bf16x8 z;
    z[0]=Xs[xb+v]; z[1]=Xs[416+xb+v]; z[2]=Xs[832+xb+v];
    z[3]=(short)f2bits(a0); z[4]=(short)f2bits(a1); z[5]=(short)f2bits(a2);
    z[6]=0; z[7]=0;
    *(bf16x8*)&Z6[tid*8] = z;
  }
  __syncthreads();

  // ---- pass 1: H1pre = Z6 @ W6 via MFMA ----
  f32x4 c1f[4][4] = {};
  #pragma unroll
  for(int vi=0; vi<4; vi++){
    int v = wid + vi*8;
    if(v < V_){
      bf16x8 af = {0,0,0,0,0,0,0,0};
      if(lane < 16) af = *(const bf16x8*)&Z6[(v*16 + lane)*8];
      #pragma unroll
      for(int n=0;n<4;n++)
        c1f[vi][n] = __builtin_amdgcn_mfma_f32_16x16x32_bf16(af, w6[n], c1f[vi][n], 0, 0, 0);
    }
  }
  __syncthreads();   // Z6/Xs dead; Zs now writable

  // ---- epilogue 1: bn1 + relu + pack into Zs (rows v*16+tl, stride 72) ----
  int l15 = lane & 15, tlb = (lane>>4)*4;
  #pragma unroll
  for(int vi=0; vi<4; vi++){
    int v = wid + vi*8;
    if(v < V_){
      #pragma unroll
      for(int n=0;n<4;n++){
        #pragma unroll
        for(int j=0;j<4;j++){
          unsigned int u = pss[(tlb+j)*64 + n*16 + l15];
          float y = c1f[vi][n][j]*bits2f((unsigned short)(u&0xffffu)) + bits2f((unsigned short)(u>>16));
          Zs[(v*16 + tlb + j)*72 + n*16 + l15] = (short)f2bits(fmaxf(y, 0.f));
        }
      }
    }
  }
  __syncthreads();

  // ---- pass 2: MFMA with in-register neighbor aggregation ----
  int cg = (lane>>4)*8;
  f32x4 accs[4][4] = {};
  #pragma unroll
  for(int vi=0; vi<4; vi++){
    int v = wid + vi*8;
    if(v < V_){
      const short* rowp = &Zs[(v*16 + l15)*72 + cg];
      bf16x8 a0 = *(const bf16x8*)rowp;
      bf16x8 a1 = *(const bf16x8*)(rowp + 32);
      float s0[8]={0,0,0,0,0,0,0,0}, s1[8]={0,0,0,0,0,0,0,0};
      int e1 = soc[v+1];
      for(int e=soc[v]; e<e1; e++){
        int u = slc[e];
        const short* np = &Zs[(u*16 + l15)*72 + cg];
        bf16x8 n0 = *(const bf16x8*)np;
        bf16x8 n1 = *(const bf16x8*)(np + 32);
        #pragma unroll
        for(int j=0;j<8;j++){ s0[j] += bits2f((unsigned short)n0[j]); s1[j] += bits2f((unsigned short)n1[j]); }
      }
      bf16x8 a2, a3;
      #pragma unroll
      for(int j=0;j<8;j++){ a2[j] = (short)f2bits(s0[j]); a3[j] = (short)f2bits(s1[j]); }
      #pragma unroll
      for(int n=0;n<4;n++){
        bf16x8 b0 = *(const bf16x8*)&WbBs[(( 0+n)*64 + lane)*8];
        accs[vi][n] = __builtin_amdgcn_mfma_f32_16x16x32_bf16(a0, b0, accs[vi][n], 0, 0, 0);
        bf16x8 b1 = *(const bf16x8*)&WbBs[(( 4+n)*64 + lane)*8];
        accs[vi][n] = __builtin_amdgcn_mfma_f32_16x16x32_bf16(a1, b1, accs[vi][n], 0, 0, 0);
        bf16x8 b2 = *(const bf16x8*)&WbBs[(( 8+n)*64 + lane)*8];
        accs[vi][n] = __builtin_amdgcn_mfma_f32_16x16x32_bf16(a2, b2, accs[vi][n], 0, 0, 0);
        bf16x8 b3 = *(const bf16x8*)&WbBs[((12+n)*64 + lane)*8];
        accs[vi][n] = __builtin_amdgcn_mfma_f32_16x16x32_bf16(a3, b3, accs[vi][n], 0, 0, 0);
      }
    }
  }
  __syncthreads();

  // ---- epilogue 2: stats + bf16 transpose via Zs ----
  f32x4 ssum[4] = {}, ssq[4] = {};
  #pragma unroll
  for(int vi=0; vi<4; vi++){
    int v = wid + vi*8;
    if(v < V_){
      #pragma unroll
      for(int n=0;n<4;n++){
        #pragma unroll
        for(int j=0;j<4;j++){
          float val = accs[vi][n][j];
          ssum[n][j] += val; ssq[n][j] += val*val;
          Zs[((tlb+j)*25 + v)*72 + n*16 + l15] = (short)f2bits(val);
        }
      }
    }
  }
  __syncthreads();

  bf16* hbout = Hout + ((size_t)b*T_ + t0)*V_*64;
  for(int c=tid; c<3200; c+=512){
    bf16x8 o = *(const bf16x8*)&Zs[(c>>3)*72 + (c&7)*8];
    *(bf16x8*)&hbout[(size_t)c*8] = o;
  }
  __syncthreads();

  float* red = (float*)Zs;
  size_t pb = ((size_t)blockIdx.x*64 + blockIdx.y)*2048;
  #pragma unroll
  for(int n=0;n<4;n++)
    #pragma unroll
    for(int j=0;j<4;j++)
      red[wid*1024 + (tlb+j)*64 + n*16 + l15] = ssum[n][j];
  __syncthreads();
  for(int i=tid; i<1024; i+=512){
    float s = 0.f;
    #pragma unroll
    for(int w=0;w<8;w++) s += red[w*1024 + i];
    part[pb + i] = s;
  }
  __syncthreads();
  #pragma unroll
  for(int n=0;n<4;n++)
    #pragma unroll
    for(int j=0;j<4;j++)
      red[wid*1024 + (tlb+j)*64 + n*16 + l15] = ssq[n][j];
  __syncthreads();
  for(int i=tid; i<1024; i+=512){
    float q = 0.f;
    #pragma unroll
    for(int w=0;w<8;w++) q += red[w*1024 + i];
    part[pb + 1024 + i] = q;
  }
}

// ---------------- conv1 via MFMA, K-split over 2 v-groups ----------------
__device__ __forceinline__ bf16x8 loadH8(const bf16* H, int b, int v, int t0, int s){
  int ti = s>>3, h0 = (s&7)*8, t = t0-1+ti;
  bf16x8 r = {0,0,0,0,0,0,0,0};
  if(t >= 0 && t < T_) r = *(const bf16x8*)&H[(((size_t)b*T_+t)*V_ + v)*HD_ + h0];
  return r;
}

__device__ __forceinline__ void xform_store(short* zbuf, const unsigned int* sshf, int s, bf16x8 raw){
  int ti = s>>3, h0 = (s&7)*8;
  uint4 u0 = *(const uint4*)&sshf[ti*64 + h0];
  uint4 u1 = *(const uint4*)&sshf[ti*64 + h0 + 4];
  unsigned int uu[8] = {u0.x,u0.y,u0.z,u0.w,u1.x,u1.y,u1.z,u1.w};
  bf16x8 outv;
  #pragma unroll
  for(int j=0;j<8;j++){
    float scl = bits2f((unsigned short)(uu[j] & 0xffffu));
    float shf = bits2f((unsigned short)(uu[j] >> 16));
    float x = bits2f((unsigned short)raw[j]);
    outv[j] = (short)f2bits(fmaxf(x*scl + shf, 0.f));
  }
  *(bf16x8*)&zbuf[ti*72 + h0] = outv;
}

__global__ __launch_bounds__(256,4) void k_conv1(
    const bf16* __restrict__ H, const float* __restrict__ scale2, const float* __restrict__ shift2,
    const bf16* __restrict__ Wb, float* __restrict__ P)
{
  int b = blockIdx.y, t0 = blockIdx.x*64, vg = blockIdx.z, tid = threadIdx.x;
  int lane = tid & 63, w = tid >> 6;
  int v0 = vg ? 13 : 0, nv = vg ? 12 : 13;
  __shared__ unsigned int sshf[66*64];
  __shared__ short zs[2][66*72];

  for(int i = tid; i < 66*64; i += 256){
    int ti = i>>6, h = i&63, t = t0-1+ti;
    unsigned int u = 0;
    if(t >= 0 && t < T_){
      u = ((unsigned)f2bits(shift2[t*64+h])<<16) | f2bits(scale2[t*64+h]);
    }
    sshf[i] = u;
  }
  __syncthreads();

  {
    bf16x8 a0 = loadH8(H,b,v0,t0,tid);
    bf16x8 a1 = loadH8(H,b,v0,t0,tid+256);
    bf16x8 a2 = {0,0,0,0,0,0,0,0};
    if(tid<16) a2 = loadH8(H,b,v0,t0,tid+512);
    xform_store(zs[0], sshf, tid, a0);
    xform_store(zs[0], sshf, tid+256, a1);
    if(tid<16) xform_store(zs[0], sshf, tid+512, a2);
  }
  __syncthreads();

  int ow = w & 1, twv = (w>>1)*32;
  int o0 = ow*32;
  f32x16 acc = {};
  for(int i=0; i<nv; i++){
    int v = v0 + i, cur = i & 1;
    bf16x8 a0={0,0,0,0,0,0,0,0}, a1={0,0,0,0,0,0,0,0}, a2={0,0,0,0,0,0,0,0};
    if(i+1 < nv){
      a0 = loadH8(H,b,v+1,t0,tid);
      a1 = loadH8(H,b,v+1,t0,tid+256);
      if(tid<16) a2 = loadH8(H,b,v+1,t0,tid+512);
    }
    const short* zbuf = zs[cur];
    #pragma unroll
    for(int kc=0; kc<12; kc++){
      int ks = kc>>2;
      bf16x8 af = *(const bf16x8*)&Wb[((v*12+kc)*64 + o0 + (lane&31))*16 + (lane>>5)*8];
      int row = twv + (lane&31) + ks;
      int col = (kc&3)*16 + (lane>>5)*8;
      bf16x8 bfr = *(const bf16x8*)&zbuf[row*72 + col];
      acc = __builtin_amdgcn_mfma_f32_32x32x16_bf16(af, bfr, acc, 0, 0, 0);
    }
    if(i+1 < nv){
      short* znext = zs[cur^1];
      xform_store(znext, sshf, tid, a0);
      xform_store(znext, sshf, tid+256, a1);
      if(tid<16) xform_store(znext, sshf, tid+512, a2);
    }
    __syncthreads();
  }
  int t = t0 + twv + (lane&31);
  size_t pbase = ((size_t)vg*B_ + b)*64;
  #pragma unroll
  for(int r=0;r<16;r++){
    int o = o0 + (r&3) + 8*(r>>2) + 4*(lane>>5);
    P[(pbase + o)*T_ + t] = acc[r];
  }
}

// ---------------- reduce partial planes -> C1 bf16 + BN3 stats ----------------
__global__ __launch_bounds__(128) void k_red1(
    const float* __restrict__ P, bf16* __restrict__ C1b,
    float* __restrict__ sum3, float* __restrict__ sq3)
{
  int o = blockIdx.x, b = blockIdx.y, tid = threadIdx.x;
  size_t base = ((size_t)b*64 + o)*T_ + tid*4;
  float4 x = *(const float4*)&P[base];
  float4 y = *(const float4*)&P[2097152 + base];
  float4 r;
  r.x = x.x + y.x; r.y = x.y + y.y; r.z = x.z + y.z; r.w = x.w + y.w;
  bf16x4 st;
  st[0]=(short)f2bits(r.x); st[1]=(short)f2bits(r.y); st[2]=(short)f2bits(r.z); st[3]=(short)f2bits(r.w);
  *(bf16x4*)&C1b[base] = st;
  float s = r.x + r.y + r.z + r.w;
  float q = r.x*r.x + r.y*r.y + r.z*r.z + r.w*r.w;
  for(int off=32; off; off>>=1){ s += __shfl_down(s, off); q += __shfl_down(q, off); }
  __shared__ float rs[2], rq[2];
  if((tid&63)==0){ rs[tid>>6]=s; rq[tid>>6]=q; }
  __syncthreads();
  if(tid==0){ atomicAdd(&sum3[o], rs[0]+rs[1]); atomicAdd(&sq3[o], rq[0]+rq[1]); }
}

// ---------------- per-channel BN finalize ----------------
__global__ void k_bnfin_ch(const float* __restrict__ sum, const float* __restrict__ sq,
                           const float* __restrict__ g, const float* __restrict__ bt,
                           float* __restrict__ scale, float* __restrict__ shift,
                           int nch, float inv_count)
{
  int i = blockIdx.x*blockDim.x + threadIdx.x;
  if(i < nch){
    float m = sum[i]*inv_count;
    float v = sq[i]*inv_count - m*m;
    float r = rsqrtf(fmaxf(v, 0.f) + 1e-5f);
    float sc = g[i]*r;
    scale[i]=sc; shift[i]=bt[i]-m*sc;
  }
}

// ---------------- conv2 via MFMA ----------------
__global__ __launch_bounds__(256) void k_conv2(
    const bf16* __restrict__ C1b, const float* __restrict__ scale3, const float* __restrict__ shift3,
    const bf16* __restrict__ Wb2, float* __restrict__ C2)
{
  int b = blockIdx.y, t0 = blockIdx.x*64, tid = threadIdx.x;
  int lane = tid & 63, w = tid >> 6;
  __shared__ short zT[68*72];
  __shared__ float scl[64], shf[64];
  if(tid < 64){ scl[tid]=scale3[tid]; shf[tid]=shift3[tid]; }
  __syncthreads();
  for(int i=tid; i<4352; i+=256){
    int c = i/68, r = i%68, t = t0 - 2 + r;
    float val = 0.f;
    if(t >= 0 && t < T_) val = fmaxf(bits2f((unsigned short)__builtin_bit_cast(short, C1b[((size_t)b*64+c)*T_ + t]))*scl[c] + shf[c], 0.f);
    zT[r*72 + c] = (short)f2bits(val);
  }
  __syncthreads();
  int o0 = w*32;
  #pragma unroll
  for(int tt=0; tt<2; tt++){
    int twv = tt*32;
    f32x16 acc = {};
    #pragma unroll
    for(int kc=0; kc<12; kc++){
      bf16x8 af = *(const bf16x8*)&Wb2[((kc*128) + o0 + (lane&31))*16 + (lane>>5)*8];
      bf16x8 bfr = *(const bf16x8*)&zT[(twv + (lane&31) + 2*(kc>>2))*72 + (kc&3)*16 + (lane>>5)*8];
      acc = __builtin_amdgcn_mfma_f32_32x32x16_bf16(af, bfr, acc, 0, 0, 0);
    }
    int t = t0 + twv + (lane&31);
    #pragma unroll
    for(int r=0;r<16;r++){
      int o = o0 + (r&3) + 8*(r>>2) + 4*(lane>>5);
      C2[((size_t)b*128 + o)*T_ + t] = acc[r];
    }
  }
}

// ---------------- per-channel stats over C2 ----------------
__global__ __launch_bounds__(256) void k_stats_ch(const float* __restrict__ C,
    float* __restrict__ sum, float* __restrict__ sq, int nch)
{
  int o = blockIdx.x, tid = threadIdx.x;
  float s=0.f, q=0.f;
  for(int idx = tid; idx < 64*128; idx += 256){
    int b = idx >> 7, t4 = idx & 127;
    float4 vv = *(const float4*)&C[((size_t)(b*nch+o))*T_ + t4*4];
    s += vv.x+vv.y+vv.z+vv.w;
    q += vv.x*vv.x + vv.y*vv.y + vv.z*vv.z + vv.w*vv.w;
  }
  for(int off=32; off; off>>=1){ s += __shfl_down(s, off); q += __shfl_down(q, off); }
  __shared__ float rs[4], rq[4];
  if((tid&63)==0){ rs[tid>>6]=s; rq[tid>>6]=q; }
  __syncthreads();
  if(tid==0){ sum[o] = rs[0]+rs[1]+rs[2]+rs[3]; sq[o] = rq[0]+rq[1]+rq[2]+rq[3]; }
}

// ---------------- head ----------------
__global__ __launch_bounds__(256) void k_head(
    const float* __restrict__ C2, const float* __restrict__ scale4, const float* __restrict__ shift4,
    const float* __restrict__ fcW, const float* __restrict__ fcb, float* __restrict__ out)
{
  int b = blockIdx.x, tid = threadIdx.x;
  __shared__ float mean[128];
  __shared__ float ms[256];
  int ch = tid >> 1, p = tid & 1;
  float scl = scale4[ch], shf = shift4[ch];
  const float* src = C2 + ((size_t)b*128 + ch)*T_ + p*256;
  float s = 0.f;
  for(int i=0;i<64;i++){
    float4 v4 = *(const float4*)&src[i*4];
    s += fmaxf(v4.x*scl + shf, 0.f) + fmaxf(v4.y*scl + shf, 0.f)
       + fmaxf(v4.z*scl + shf, 0.f) + fmaxf(v4.w*scl + shf, 0.f);
  }
  ms[tid] = s;
  __syncthreads();
  if(tid < 128) mean[tid] = (ms[2*tid] + ms[2*tid+1]) * (1.0f/512.0f);
  __syncthreads();
  if(tid < NC_){
    float acc = fcb[tid];
    for(int c=0;c<128;c++) acc += mean[c]*fcW[c*NC_ + tid];
    out[b*NC_ + tid] = acc;
  }
}

// ---------------- launch ----------------
extern "C" void kernel_launch(void* const* d_in, const int* in_sizes, int n_in,
                              void* d_out, int out_size, void* d_ws, size_t ws_size,
                              hipStream_t stream)
{
  const float* X   = (const float*)d_in[0];
  const int*   ei  = (const int*)  d_in[1];
  const float* W1  = (const float*)d_in[2];
  const float* s1W = (const float*)d_in[3];
  const float* g1  = (const float*)d_in[5];
  const float* b1  = (const float*)d_in[6];
  const float* W2  = (const float*)d_in[7];
  const float* s2W = (const float*)d_in[8];
  const float* g2  = (const float*)d_in[10];
  const float* b2  = (const float*)d_in[11];
  const float* c1W = (const float*)d_in[12];
  const float* tg1 = (const float*)d_in[14];
  const float* tb1 = (const float*)d_in[15];
  const float* c2W = (const float*)d_in[16];
  const float* tg2 = (const float*)d_in[18];
  const float* tb2 = (const float*)d_in[19];
  const float* fcW = (const float*)d_in[20];
  const float* fcb = (const float*)d_in[21];

  char* ws = (char*)d_ws;
  bf16*  H     = (bf16*) (ws);                       // H2, 104,857,600 B
  bf16*  C1b   = (bf16*) (ws + 104857600);           // 4 MB bf16
  float* part  = (float*)(ws + 113246208);           // 16.7 MB multi-use: partials -> P -> C2
  float* P     = part;
  float* C2    = part;
  bf16*  Wb    = (bf16*) (ws + 130023424);
  bf16*  Wb2   = (bf16*) (ws + 131252224);
  bf16*  WbB   = (bf16*) (ws + 131350528);
  float* stats = (float*)(ws + 131366912);
  bf16*  W6f   = (bf16*) (stats);                    // 4 KB in unused stats head
  float* sum3 = stats + 131072;   float* sq3 = sum3 + 64;
  float* sum4 = sq3 + 64;         float* sq4 = sum4 + 128;
  float* scale1 = stats + 131456; float* shift1 = scale1 + 32768;
  float* scale2 = shift1 + 32768; float* shift2 = scale2 + 32768;
  float* scale3 = shift2 + 32768; float* shift3 = scale3 + 64;
  float* scale4 = shift3 + 64;    float* shift4 = scale4 + 128;
  int* csr_off = (int*)(shift4 + 128);
  int* csr_lst = csr_off + 32;

  hipMemsetAsync(sum3, 0, 384*sizeof(float), stream);
  k_csr<<<1, 64, 0, stream>>>(ei, csr_off, csr_lst);
  k_wt<<<256, 256, 0, stream>>>(c1W, c2W, s2W, W2, s1W, W1, Wb, Wb2, WbB, W6f);

  k_gcn1s<<<dim3(T_/16, B_), 512, 0, stream>>>(X, W6f, csr_off, csr_lst, part);
  k_bnfin_th<<<128, 256, 0, stream>>>(part, g1, b1, scale1, shift1);
  k_gcn2<<<dim3(T_/16, B_), 512, 0, stream>>>(X, scale1, shift1, W6f, WbB, csr_off, csr_lst, H, part);
  k_bnfin_th<<<128, 256, 0, stream>>>(part, g2, b2, scale2, shift2);
  k_conv1<<<dim3(8, B_, 2), 256, 0, stream>>>(H, scale2, shift2, Wb, P);
  k_red1<<<dim3(64, B_), 128, 0, stream>>>(P, C1b, sum3, sq3);
  k_bnfin_ch<<<1, 64, 0, stream>>>(sum3, sq3, tg1, tb1, scale3, shift3, 64, 1.0f/32768.0f);
  k_conv2<<<dim3(8, B_), 256, 0, stream>>>(C1b, scale3, shift3, Wb2, C2);
  k_stats_ch<<<128, 256, 0, stream>>>(C2, sum4, sq4, 128);
  k_bnfin_ch<<<1, 128, 0, stream>>>(sum4, sq4, tg2, tb2, scale4, shift4, 128, 1.0f/32768.0f);
  k_head<<<B_, 256, 0, stream>>>(C2, scale4, shift4, fcW, fcb, (float*)d_out);
}